// Round 7
// baseline (130.470 us; speedup 1.0000x reference)
//
#include <hip/hip_runtime.h>

#define BN 4096
#define DIM 256
#define NBLK 32              // 4096/128 row-blocks
#define NPAIR 528            // NBLK*(NBLK+1)/2 upper-tri block pairs
#define MARGIN_F 0.3f
#define NEG_FILL_F 1e9f
#define HP_SENT_BITS 0xBF800000  // bits of -1.0f: "no positive seen"

typedef __attribute__((ext_vector_type(8))) __bf16 bf16x8;
typedef __attribute__((ext_vector_type(4))) float f32x4;

// fp32 -> bf16 round-to-nearest-even (inputs are normal floats, no NaN/Inf)
__device__ __forceinline__ ushort f2bf(float x) {
    unsigned u = __float_as_uint(x);
    return (ushort)((u + 0x7FFFu + ((u >> 16) & 1u)) >> 16);
}
__device__ __forceinline__ float bf2f(ushort b) {
    return __uint_as_float(((unsigned)b) << 16);
}

// ---------------- prep: norms + red/counter zero + bf16 hi/lo split --------------
// Ehi/Elo are ROW-MAJOR bf16 [row][k] (2 MB each) — MFMA frags load directly
// from global: one 64B line (row, k0..31) serves all 4 quads of a frag load.
__global__ __launch_bounds__(256) void tl_prep(const float* __restrict__ E,
                                               float* __restrict__ norms,
                                               float* __restrict__ red,
                                               ushort* __restrict__ Ehi,
                                               ushort* __restrict__ Elo) {
    const int tid  = threadIdx.x;
    const int lane = tid & 63;
    const int row  = blockIdx.x * 4 + (tid >> 6);

    float4 v = reinterpret_cast<const float4*>(E + (size_t)row * DIM)[lane];
    float f[4] = {v.x, v.y, v.z, v.w};
    ushort hb[4], lb[4];
    float s = 0.0f;
    #pragma unroll
    for (int q = 0; q < 4; ++q) {
        s += f[q] * f[q];
        hb[q] = f2bf(f[q]);
        lb[q] = f2bf(f[q] - bf2f(hb[q]));
    }
    const size_t co = (size_t)row * DIM + lane * 4;   // row-major, coalesced 8B/lane
    *reinterpret_cast<ushort4*>(Ehi + co) = make_ushort4(hb[0], hb[1], hb[2], hb[3]);
    *reinterpret_cast<ushort4*>(Elo + co) = make_ushort4(lb[0], lb[1], lb[2], lb[3]);

    #pragma unroll
    for (int m = 32; m; m >>= 1) s += __shfl_xor(s, m, 64);
    if (lane == 0) norms[row] = s;
    if (blockIdx.x == 0 && tid < 3) red[tid] = 0.0f;  // [0]=sum [1]=cnt [2]=ticket
}

// ---------------- main: LDS-free register-direct split-bf16 MFMA Gram ------------
// One block per upper-tri 128x128 pair. 4 waves, each a 64x64 sub-tile.
// NO staging LDS, NO K-loop barriers: each wave streams MFMA fragments straight
// from L2-resident row-major bf16 panels (fully unrolled 8-step K-loop).
// Results leave via PLAIN stores to collision-free partial slots:
//   row-part of pair (ib,jb) -> slot jb;  col-part -> slot ib;  diagonal combined.
__global__ __launch_bounds__(256, 3) void tl_main(const ushort* __restrict__ Ehi,
                                                  const ushort* __restrict__ Elo,
                                                  const int* __restrict__ labels,
                                                  const float* __restrict__ norms,
                                                  float* __restrict__ pHP,
                                                  float* __restrict__ pHN) {
    __shared__ int comb[512];   // epilogue block-combine only (2 KB)

    const int tid  = threadIdx.x;
    const int lane = tid & 63;
    const int wave = tid >> 6;
    const int wy = wave >> 1, wx = wave & 1;
    const int quad = lane >> 4, l15 = lane & 15;

    // decode blockIdx -> (ib <= jb) upper-tri pair
    int t = blockIdx.x, ib = 0, off = 0;
    while (off + (NBLK - ib) <= t) { off += NBLK - ib; ++ib; }
    const int jb = ib + (t - off);
    const int i0 = ib * 128, j0 = jb * 128;

    // frag base addresses (elements): A row = i0+wy*64+r*16+l15, k = quad*8
    const size_t aBase = ((size_t)(i0 + wy * 64 + l15)) * DIM + quad * 8;
    const size_t bBase = ((size_t)(j0 + wx * 64 + l15)) * DIM + quad * 8;

    f32x4 acc[4][4];
    #pragma unroll
    for (int r = 0; r < 4; ++r)
        #pragma unroll
        for (int c = 0; c < 4; ++c)
            acc[r][c] = (f32x4){0.f, 0.f, 0.f, 0.f};

    #pragma unroll
    for (int kb = 0; kb < DIM / 32; ++kb) {
        const size_t ko = (size_t)kb * 32;
        bf16x8 ah[4], al[4], bh[4], bl[4];
        #pragma unroll
        for (int r = 0; r < 4; ++r) {
            const size_t ia = aBase + (size_t)(r * 16) * DIM + ko;
            ah[r] = *reinterpret_cast<const bf16x8*>(Ehi + ia);
            al[r] = *reinterpret_cast<const bf16x8*>(Elo + ia);
        }
        #pragma unroll
        for (int c = 0; c < 4; ++c) {
            const size_t jb_ = bBase + (size_t)(c * 16) * DIM + ko;
            bh[c] = *reinterpret_cast<const bf16x8*>(Ehi + jb_);
            bl[c] = *reinterpret_cast<const bf16x8*>(Elo + jb_);
        }
        #pragma unroll
        for (int c = 0; c < 4; ++c)
            #pragma unroll
            for (int r = 0; r < 4; ++r) {
                acc[r][c] = __builtin_amdgcn_mfma_f32_16x16x32_bf16(ah[r], bh[c], acc[r][c], 0, 0, 0);
                acc[r][c] = __builtin_amdgcn_mfma_f32_16x16x32_bf16(ah[r], bl[c], acc[r][c], 0, 0, 0);
                acc[r][c] = __builtin_amdgcn_mfma_f32_16x16x32_bf16(al[r], bh[c], acc[r][c], 0, 0, 0);
            }
    }

    // ---- epilogue: dots -> distances -> masked row & col stats ----
    // C layout (16x16x32): col = lane&15, row = quad*4 + reg  [m89/m91]
    const int rowBase = i0 + wy * 64;
    const int colBase = j0 + wx * 64;

    float nrow[4][4]; int lrow[4][4];
    #pragma unroll
    for (int r = 0; r < 4; ++r)
        #pragma unroll
        for (int e = 0; e < 4; ++e) {
            const int g = rowBase + r * 16 + quad * 4 + e;
            nrow[r][e] = norms[g];
            lrow[r][e] = labels[g];
        }
    float ncol[4]; int lcol[4];
    #pragma unroll
    for (int c = 0; c < 4; ++c) {
        const int g = colBase + c * 16 + l15;
        ncol[c] = norms[g];
        lcol[c] = labels[g];
    }

    float rmax[4][4], rmin[4][4], cmax[4], cmin[4];
    #pragma unroll
    for (int r = 0; r < 4; ++r)
        #pragma unroll
        for (int e = 0; e < 4; ++e) { rmax[r][e] = -1.0f; rmin[r][e] = NEG_FILL_F; }
    #pragma unroll
    for (int c = 0; c < 4; ++c) { cmax[c] = -1.0f; cmin[c] = NEG_FILL_F; }

    #pragma unroll
    for (int c = 0; c < 4; ++c) {
        const int gcol = colBase + c * 16 + l15;
        #pragma unroll
        for (int r = 0; r < 4; ++r) {
            #pragma unroll
            for (int e = 0; e < 4; ++e) {
                const int grow = rowBase + r * 16 + quad * 4 + e;
                float d2 = nrow[r][e] + ncol[c] - 2.0f * acc[r][c][e];
                d2 = fmaxf(d2, 0.0f);
                const float d = (d2 > 0.0f) ? sqrtf(d2) : 0.0f;
                if (lrow[r][e] == lcol[c]) {
                    if (grow != gcol) {
                        rmax[r][e] = fmaxf(rmax[r][e], d);
                        cmax[c]    = fmaxf(cmax[c], d);
                    }
                } else {
                    rmin[r][e] = fminf(rmin[r][e], d);
                    cmin[c]    = fminf(cmin[c], d);
                }
            }
        }
    }

    #pragma unroll
    for (int m = 1; m <= 8; m <<= 1) {          // row stats across lane bits 0..3
        #pragma unroll
        for (int r = 0; r < 4; ++r)
            #pragma unroll
            for (int e = 0; e < 4; ++e) {
                rmax[r][e] = fmaxf(rmax[r][e], __shfl_xor(rmax[r][e], m, 64));
                rmin[r][e] = fminf(rmin[r][e], __shfl_xor(rmin[r][e], m, 64));
            }
    }
    #pragma unroll
    for (int m = 16; m <= 32; m <<= 1) {        // col stats across quads
        #pragma unroll
        for (int c = 0; c < 4; ++c) {
            cmax[c] = fmaxf(cmax[c], __shfl_xor(cmax[c], m, 64));
            cmin[c] = fminf(cmin[c], __shfl_xor(cmin[c], m, 64));
        }
    }

    // block-level combine in LDS (CU-local atomics; signed-int encoding so the
    // -1.0f sentinel orders correctly), then PLAIN global stores to partial slots.
    int*      srhp = comb;                                   // [128]
    unsigned* srhn = reinterpret_cast<unsigned*>(comb + 128);
    int*      schp = comb + 256;
    unsigned* schn = reinterpret_cast<unsigned*>(comb + 384);
    if (tid < 128) {
        srhp[tid] = (int)HP_SENT_BITS;
        srhn[tid] = __float_as_uint(NEG_FILL_F);
        schp[tid] = (int)HP_SENT_BITS;
        schn[tid] = __float_as_uint(NEG_FILL_F);
    }
    __syncthreads();
    if (l15 == 0) {   // lanes 0,16,32,48 hold row results for their quad
        #pragma unroll
        for (int r = 0; r < 4; ++r)
            #pragma unroll
            for (int e = 0; e < 4; ++e) {
                const int lr = wy * 64 + r * 16 + quad * 4 + e;
                atomicMax(&srhp[lr], __float_as_int(rmax[r][e]));
                atomicMin(&srhn[lr], __float_as_uint(rmin[r][e]));
            }
    }
    if (quad == 0) {  // lanes 0..15 hold col results
        #pragma unroll
        for (int c = 0; c < 4; ++c) {
            const int lc = wx * 64 + c * 16 + l15;
            atomicMax(&schp[lc], __float_as_int(cmax[c]));
            atomicMin(&schn[lc], __float_as_uint(cmin[c]));
        }
    }
    __syncthreads();
    if (tid < 128) {
        float rp = __int_as_float(srhp[tid]);
        float rn = __uint_as_float(srhn[tid]);
        const float cp = __int_as_float(schp[tid]);
        const float cn = __uint_as_float(schn[tid]);
        if (ib == jb) {
            pHP[(size_t)jb * BN + i0 + tid] = fmaxf(rp, cp);   // diagonal: combine
            pHN[(size_t)jb * BN + i0 + tid] = fminf(rn, cn);
        } else {
            pHP[(size_t)jb * BN + i0 + tid] = rp;   // row-part -> slot jb
            pHN[(size_t)jb * BN + i0 + tid] = rn;
            pHP[(size_t)ib * BN + j0 + tid] = cp;   // col-part -> slot ib
            pHN[(size_t)ib * BN + j0 + tid] = cn;
        }
    }
}

// ------- reduce: fold 32 partial slots per row, accumulate loss, last block final -
__global__ __launch_bounds__(256) void tl_reduce(const float* __restrict__ pHP,
                                                 const float* __restrict__ pHN,
                                                 float* __restrict__ red,
                                                 float* __restrict__ out) {
    const int i = blockIdx.x * 256 + threadIdx.x;    // one row per thread
    float hp = -1.0f, hn = NEG_FILL_F;
    #pragma unroll
    for (int s = 0; s < NBLK; ++s) {
        hp = fmaxf(hp, pHP[(size_t)s * BN + i]);     // coalesced per wave
        hn = fminf(hn, pHN[(size_t)s * BN + i]);
    }
    const bool valid = (hp >= 0.0f) && (hn < NEG_FILL_F);  // has_pos && has_neg
    const float per = fmaxf(hp - hn + MARGIN_F, 0.0f);
    float s_ = valid ? per : 0.0f;
    float c_ = valid ? 1.0f : 0.0f;
    #pragma unroll
    for (int m = 32; m; m >>= 1) {
        s_ += __shfl_xor(s_, m, 64);
        c_ += __shfl_xor(c_, m, 64);
    }
    __shared__ float as_[4], ac_[4];
    const int wid = threadIdx.x >> 6;
    if ((threadIdx.x & 63) == 0) { as_[wid] = s_; ac_[wid] = c_; }
    __syncthreads();
    if (threadIdx.x == 0) {
        const float S = as_[0] + as_[1] + as_[2] + as_[3];
        const float C = ac_[0] + ac_[1] + ac_[2] + ac_[3];
        atomicAdd(&red[0], S);
        atomicAdd(&red[1], C);
        __threadfence();
        const unsigned ticket = atomicAdd(reinterpret_cast<unsigned*>(&red[2]), 1u);
        if (ticket == gridDim.x - 1) {               // last block finalizes
            const float S2 = atomicAdd(&red[0], 0.0f);   // atomic read (RMW-ordered)
            const float C2 = atomicAdd(&red[1], 0.0f);
            out[0] = (C2 > 0.0f) ? (S2 / fmaxf(C2, 1.0f)) : 0.0f;
        }
    }
}

extern "C" void kernel_launch(void* const* d_in, const int* in_sizes, int n_in,
                              void* d_out, int out_size, void* d_ws, size_t ws_size,
                              hipStream_t stream) {
    const float* E      = (const float*)d_in[0];
    const int*   labels = (const int*)d_in[1];

    float*  ws    = (float*)d_ws;
    float*  norms = ws;                            // [4096] f32
    float*  red   = ws + 4096;                     // [3] f32 (sum, cnt, ticket)
    float*  pHP   = ws + 8192;                     // [32][4096] f32 = 512 KB
    float*  pHN   = ws + 8192 + NBLK * BN;         // [32][4096] f32 = 512 KB
    ushort* Ehi   = (ushort*)(ws + 8192 + 2 * NBLK * BN);  // [4096][256] bf16 = 2 MB
    ushort* Elo   = Ehi + (size_t)BN * DIM;        // 2 MB

    tl_prep<<<BN / 4, 256, 0, stream>>>(E, norms, red, Ehi, Elo);
    tl_main<<<NPAIR, 256, 0, stream>>>(Ehi, Elo, labels, norms, pHP, pHN);
    tl_reduce<<<BN / 256, 256, 0, stream>>>(pHP, pHN, red, (float*)d_out);
}

// Round 8
// 98.698 us; speedup vs baseline: 1.3219x; 1.3219x over previous
//
#include <hip/hip_runtime.h>
#include <hip/hip_fp16.h>

#define BN 4096
#define DIM 256
#define NBLK 32              // 4096/128 row-blocks
#define NPAIR 528            // NBLK*(NBLK+1)/2 upper-tri block pairs
#define MARGIN_F 0.3f
#define NEG_FILL_F 1e9f
#define HP_SENT_BITS 0xBF800000  // bits of -1.0f: "no positive seen"

typedef __attribute__((ext_vector_type(8))) _Float16 f16x8;
typedef __attribute__((ext_vector_type(4))) float f32x4;

// async global->LDS, 16B per lane; LDS dest: wave-uniform base + lane*16
__device__ __forceinline__ void gld_lds16(const void* g, void* l) {
    __builtin_amdgcn_global_load_lds(
        (const __attribute__((address_space(1))) unsigned int*)g,
        (__attribute__((address_space(3))) unsigned int*)l, 16, 0, 0);
}

// ---------------- prep: norms (exact fp32) + red zero + fp16 panel ---------------
// Eh global layout is chunk-major: [kc = k/8][row][8 f16], 16B per (kc,row) chunk.
__global__ __launch_bounds__(256) void tl_prep(const float* __restrict__ E,
                                               float* __restrict__ norms,
                                               float* __restrict__ red,
                                               ushort* __restrict__ Eh) {
    const int tid  = threadIdx.x;
    const int lane = tid & 63;
    const int row  = blockIdx.x * 4 + (tid >> 6);

    float4 v = reinterpret_cast<const float4*>(E + (size_t)row * DIM)[lane];
    float f[4] = {v.x, v.y, v.z, v.w};
    ushort hb[4];
    float s = 0.0f;
    #pragma unroll
    for (int q = 0; q < 4; ++q) {
        s += f[q] * f[q];                       // norm from ORIGINAL fp32 (exact)
        hb[q] = __half_as_ushort(__float2half(f[q]));   // RN convert
    }
    // lane holds k = lane*4..lane*4+3 -> chunk kc = lane/2, half = lane&1
    const int kc = lane >> 1, half = lane & 1;
    const size_t co = (((size_t)(kc * BN + row)) << 3) + (size_t)(half * 4);
    *reinterpret_cast<ushort4*>(Eh + co) = make_ushort4(hb[0], hb[1], hb[2], hb[3]);

    #pragma unroll
    for (int m = 32; m; m >>= 1) s += __shfl_xor(s, m, 64);
    if (lane == 0) norms[row] = s;
    if (blockIdx.x == 0 && tid < 3) red[tid] = 0.0f;  // [0]=sum [1]=cnt [2]=ticket
}

// ---------------- main: single-fp16 MFMA Gram + fused distance/masked min-max ----
// One block per upper-tri 128x128 pair. 4 waves, each a 64x64 sub-tile.
// BK=64 double-buffered LDS (2 x 32 KB): 4 barrier-drains per block (was 8).
// Results leave via PLAIN stores to collision-free partial slots (no global atomics).
__global__ __launch_bounds__(256) void tl_main(const ushort* __restrict__ Eh,
                                               const int* __restrict__ labels,
                                               const float* __restrict__ norms,
                                               float* __restrict__ pHP,
                                               float* __restrict__ pHN) {
    // Per buffer: A chunks [kc 0..7][m 0..127] then B chunks [kc 0..7][m 0..127],
    // 16B each -> 2048 chunks = 32 KB.
    __shared__ __align__(16) ushort smem[2][16384];

    const int tid  = threadIdx.x;
    const int lane = tid & 63;
    const int wave = tid >> 6;
    const int wy = wave >> 1, wx = wave & 1;
    const int quad = lane >> 4, l15 = lane & 15;

    // decode blockIdx -> (ib <= jb) upper-tri pair
    int t = blockIdx.x, ib = 0, off = 0;
    while (off + (NBLK - ib) <= t) { off += NBLK - ib; ++ib; }
    const int jb = ib + (t - off);
    const int i0 = ib * 128, j0 = jb * 128;

    f32x4 acc[4][4];
    #pragma unroll
    for (int r = 0; r < 4; ++r)
        #pragma unroll
        for (int c = 0; c < 4; ++c)
            acc[r][c] = (f32x4){0.f, 0.f, 0.f, 0.f};

    // stage one 64-k slab (A 128 rows + B 128 rows) into buffer `buf`
    auto stage = [&](int kb, int buf) {
        #pragma unroll
        for (int s = 0; s < 8; ++s) {
            const int idx  = s * 256 + tid;          // 2048 16B chunks
            const int part = idx >> 10;              // 0:A 1:B
            const int kc   = (idx >> 7) & 7;         // k-chunk within BK=64
            const int m    = idx & 127;
            const int base = part ? j0 : i0;
            const ushort* src = Eh + (((size_t)((kb * 8 + kc) * BN + base + m)) << 3);
            gld_lds16(src, &smem[buf][idx << 3]);
        }
    };

    stage(0, 0);
    #pragma unroll
    for (int kb = 0; kb < DIM / 64; ++kb) {          // 4 steps
        const int buf = kb & 1;
        __syncthreads();                   // drain stage(kb); protect buf^1 readers
        if (kb + 1 < DIM / 64) stage(kb + 1, buf ^ 1);

        const ushort* sb = &smem[buf][0];
        #pragma unroll
        for (int h = 0; h < 2; ++h) {                // two K=32 halves per slab
            f16x8 a[4], b[4];
            #pragma unroll
            for (int r = 0; r < 4; ++r) {
                const int mi = wy * 64 + r * 16 + l15;
                a[r] = *reinterpret_cast<const f16x8*>(&sb[(((h * 4 + quad) * 128) + mi) * 8]);
            }
            #pragma unroll
            for (int c = 0; c < 4; ++c) {
                const int ni = wx * 64 + c * 16 + l15;
                b[c] = *reinterpret_cast<const f16x8*>(&sb[((1024 + (h * 4 + quad) * 128) + ni) * 8]);
            }
            #pragma unroll
            for (int c = 0; c < 4; ++c)
                #pragma unroll
                for (int r = 0; r < 4; ++r)
                    acc[r][c] = __builtin_amdgcn_mfma_f32_16x16x32_f16(a[r], b[c], acc[r][c], 0, 0, 0);
        }
    }

    // ---- epilogue: dots -> distances -> masked row & col stats ----
    // C layout (16x16x32): col = lane&15, row = quad*4 + reg  [m89/m91, dtype-indep]
    const int rowBase = i0 + wy * 64;
    const int colBase = j0 + wx * 64;

    float nrow[4][4]; int lrow[4][4];
    #pragma unroll
    for (int r = 0; r < 4; ++r)
        #pragma unroll
        for (int e = 0; e < 4; ++e) {
            const int g = rowBase + r * 16 + quad * 4 + e;
            nrow[r][e] = norms[g];
            lrow[r][e] = labels[g];
        }
    float ncol[4]; int lcol[4];
    #pragma unroll
    for (int c = 0; c < 4; ++c) {
        const int g = colBase + c * 16 + l15;
        ncol[c] = norms[g];
        lcol[c] = labels[g];
    }

    float rmax[4][4], rmin[4][4], cmax[4], cmin[4];
    #pragma unroll
    for (int r = 0; r < 4; ++r)
        #pragma unroll
        for (int e = 0; e < 4; ++e) { rmax[r][e] = -1.0f; rmin[r][e] = NEG_FILL_F; }
    #pragma unroll
    for (int c = 0; c < 4; ++c) { cmax[c] = -1.0f; cmin[c] = NEG_FILL_F; }

    #pragma unroll
    for (int c = 0; c < 4; ++c) {
        const int gcol = colBase + c * 16 + l15;
        #pragma unroll
        for (int r = 0; r < 4; ++r) {
            #pragma unroll
            for (int e = 0; e < 4; ++e) {
                const int grow = rowBase + r * 16 + quad * 4 + e;
                float d2 = nrow[r][e] + ncol[c] - 2.0f * acc[r][c][e];
                d2 = fmaxf(d2, 0.0f);
                const float d = (d2 > 0.0f) ? sqrtf(d2) : 0.0f;
                if (lrow[r][e] == lcol[c]) {
                    if (grow != gcol) {
                        rmax[r][e] = fmaxf(rmax[r][e], d);
                        cmax[c]    = fmaxf(cmax[c], d);
                    }
                } else {
                    rmin[r][e] = fminf(rmin[r][e], d);
                    cmin[c]    = fminf(cmin[c], d);
                }
            }
        }
    }

    #pragma unroll
    for (int m = 1; m <= 8; m <<= 1) {          // row stats across lane bits 0..3
        #pragma unroll
        for (int r = 0; r < 4; ++r)
            #pragma unroll
            for (int e = 0; e < 4; ++e) {
                rmax[r][e] = fmaxf(rmax[r][e], __shfl_xor(rmax[r][e], m, 64));
                rmin[r][e] = fminf(rmin[r][e], __shfl_xor(rmin[r][e], m, 64));
            }
    }
    #pragma unroll
    for (int m = 16; m <= 32; m <<= 1) {        // col stats across quads
        #pragma unroll
        for (int c = 0; c < 4; ++c) {
            cmax[c] = fmaxf(cmax[c], __shfl_xor(cmax[c], m, 64));
            cmin[c] = fminf(cmin[c], __shfl_xor(cmin[c], m, 64));
        }
    }

    // block-level combine in LDS (CU-local atomics; signed-int encoding so the
    // -1.0f sentinel orders correctly), then PLAIN global stores to partial slots.
    int*      srhp = reinterpret_cast<int*>(&smem[0][0]);        // [128]
    unsigned* srhn = reinterpret_cast<unsigned*>(srhp + 128);
    int*      schp = srhp + 256;
    unsigned* schn = reinterpret_cast<unsigned*>(srhp + 384);
    __syncthreads();                  // all frag reads done; smem reusable
    if (tid < 128) {
        srhp[tid] = (int)HP_SENT_BITS;
        srhn[tid] = __float_as_uint(NEG_FILL_F);
        schp[tid] = (int)HP_SENT_BITS;
        schn[tid] = __float_as_uint(NEG_FILL_F);
    }
    __syncthreads();
    if (l15 == 0) {   // lanes 0,16,32,48 hold row results for their quad
        #pragma unroll
        for (int r = 0; r < 4; ++r)
            #pragma unroll
            for (int e = 0; e < 4; ++e) {
                const int lr = wy * 64 + r * 16 + quad * 4 + e;
                atomicMax(&srhp[lr], __float_as_int(rmax[r][e]));
                atomicMin(&srhn[lr], __float_as_uint(rmin[r][e]));
            }
    }
    if (quad == 0) {  // lanes 0..15 hold col results
        #pragma unroll
        for (int c = 0; c < 4; ++c) {
            const int lc = wx * 64 + c * 16 + l15;
            atomicMax(&schp[lc], __float_as_int(cmax[c]));
            atomicMin(&schn[lc], __float_as_uint(cmin[c]));
        }
    }
    __syncthreads();
    if (tid < 128) {
        float rp = __int_as_float(srhp[tid]);
        float rn = __uint_as_float(srhn[tid]);
        const float cp = __int_as_float(schp[tid]);
        const float cn = __uint_as_float(schn[tid]);
        if (ib == jb) {
            pHP[(size_t)jb * BN + i0 + tid] = fmaxf(rp, cp);   // diagonal: combine
            pHN[(size_t)jb * BN + i0 + tid] = fminf(rn, cn);
        } else {
            pHP[(size_t)jb * BN + i0 + tid] = rp;   // row-part -> slot jb
            pHN[(size_t)jb * BN + i0 + tid] = rn;
            pHP[(size_t)ib * BN + j0 + tid] = cp;   // col-part -> slot ib
            pHN[(size_t)ib * BN + j0 + tid] = cn;
        }
    }
}

// ------- reduce: fold 32 partial slots per row, accumulate loss, last block final -
__global__ __launch_bounds__(256) void tl_reduce(const float* __restrict__ pHP,
                                                 const float* __restrict__ pHN,
                                                 float* __restrict__ red,
                                                 float* __restrict__ out) {
    const int i = blockIdx.x * 256 + threadIdx.x;    // one row per thread
    float hp = -1.0f, hn = NEG_FILL_F;
    #pragma unroll
    for (int s = 0; s < NBLK; ++s) {
        hp = fmaxf(hp, pHP[(size_t)s * BN + i]);     // coalesced per wave
        hn = fminf(hn, pHN[(size_t)s * BN + i]);
    }
    const bool valid = (hp >= 0.0f) && (hn < NEG_FILL_F);  // has_pos && has_neg
    const float per = fmaxf(hp - hn + MARGIN_F, 0.0f);
    float s_ = valid ? per : 0.0f;
    float c_ = valid ? 1.0f : 0.0f;
    #pragma unroll
    for (int m = 32; m; m >>= 1) {
        s_ += __shfl_xor(s_, m, 64);
        c_ += __shfl_xor(c_, m, 64);
    }
    __shared__ float as_[4], ac_[4];
    const int wid = threadIdx.x >> 6;
    if ((threadIdx.x & 63) == 0) { as_[wid] = s_; ac_[wid] = c_; }
    __syncthreads();
    if (threadIdx.x == 0) {
        const float S = as_[0] + as_[1] + as_[2] + as_[3];
        const float C = ac_[0] + ac_[1] + ac_[2] + ac_[3];
        atomicAdd(&red[0], S);
        atomicAdd(&red[1], C);
        __threadfence();
        const unsigned ticket = atomicAdd(reinterpret_cast<unsigned*>(&red[2]), 1u);
        if (ticket == gridDim.x - 1) {               // last block finalizes
            const float S2 = atomicAdd(&red[0], 0.0f);   // atomic read (RMW-ordered)
            const float C2 = atomicAdd(&red[1], 0.0f);
            out[0] = (C2 > 0.0f) ? (S2 / fmaxf(C2, 1.0f)) : 0.0f;
        }
    }
}

extern "C" void kernel_launch(void* const* d_in, const int* in_sizes, int n_in,
                              void* d_out, int out_size, void* d_ws, size_t ws_size,
                              hipStream_t stream) {
    const float* E      = (const float*)d_in[0];
    const int*   labels = (const int*)d_in[1];

    float*  ws    = (float*)d_ws;
    float*  norms = ws;                            // [4096] f32
    float*  red   = ws + 4096;                     // [3] f32 (sum, cnt, ticket)
    float*  pHP   = ws + 8192;                     // [32][4096] f32 = 512 KB
    float*  pHN   = ws + 8192 + NBLK * BN;         // [32][4096] f32 = 512 KB
    ushort* Eh    = (ushort*)(ws + 8192 + 2 * NBLK * BN);  // [32][4096][8] f16 = 2 MB

    tl_prep<<<BN / 4, 256, 0, stream>>>(E, norms, red, Eh);
    tl_main<<<NPAIR, 256, 0, stream>>>(Eh, labels, norms, pHP, pHN);
    tl_reduce<<<BN / 256, 256, 0, stream>>>(pHP, pHN, red, (float*)d_out);
}